// Round 5
// baseline (348.306 us; speedup 1.0000x reference)
//
#include <hip/hip_runtime.h>

// conv2d NCHW fp32: X[32,64,112,112] * W[128,64,3,3], pad=1 -> out[32,128,112,112].
//
// v5: revert to the R3-verified conv_lds structure (ring was neutral: weight
// re-staging costs ~2us, not worth its barriers/VGPRs). New: XCD data
// affinity — XCD k writes AND reads Xt for b in [4k,4k+4) (prep stores land
// in the local L2; conv's Xt staging hits local L2 instead of L3), per-XCD
// swizzled weight copies (590 KB) so Ws staging is always L2-local, and
// prep_weights fused into the prep kernel (one less launch). K-loop, swizzle
// and fragment mapping byte-identical to R3-passed code.

typedef __attribute__((ext_vector_type(8))) __bf16 bf16x8;
typedef __attribute__((ext_vector_type(4))) float f32x4;
typedef __attribute__((ext_vector_type(4))) unsigned int u32x4;

#define XROW 7296       // shorts per Xt (b,hp) row: 114 wp * 64 c
#define WPROW 114       // LDS wp rows per staged input row
#define WS_SHORTS 73728 // one swizzled weight copy: 9*128*64

__device__ __forceinline__ unsigned short f2bf(float f) {
    unsigned u = __builtin_bit_cast(unsigned, f);
    u += 0x7FFF + ((u >> 16) & 1);  // round-to-nearest-even
    return (unsigned short)(u >> 16);
}

__device__ __forceinline__ void gload_lds16(const unsigned short* g, unsigned short* l) {
    __builtin_amdgcn_global_load_lds(
        (const __attribute__((address_space(1))) unsigned int*)g,
        (__attribute__((address_space(3))) unsigned int*)l, 16, 0, 0);
}
__device__ __forceinline__ void gload_lds4(const unsigned short* g, unsigned short* l) {
    __builtin_amdgcn_global_load_lds(
        (const __attribute__((address_space(1))) unsigned int*)g,
        (__attribute__((address_space(3))) unsigned int*)l, 4, 0, 0);
}

// ---- prep (fast path): weights + input transpose fused ----
// Weights: W[f][c][kh][kw] fp32 -> wsS[xcd][off][f][slot] bf16, slot s of row
// f holds c-octet s^(f&7) (linear LDS copy => conflict-free b128 A-reads).
// 8 copies so every XCD stages from its own L2.
// Input: X[b][c][h][w] f32 -> Xt[b][hp][wp][c] bf16, zero halo (hp=h+1,
// wp=w+1). Block bx handles (b,h) with b = (bx&7)*4 + (bx>>3)/112 — the SAME
// XCD that will consume these rows in conv_lds writes them (L2 affinity).
__global__ __launch_bounds__(512, 4)
void prep_all(const float* __restrict__ x, const float* __restrict__ flt,
              unsigned short* __restrict__ xt, unsigned short* __restrict__ wsS) {
    __shared__ __align__(16) unsigned short T[112 * 64];
    const int tid = threadIdx.x;
    const int bx  = blockIdx.x;

    // -- weight slice (first 144 blocks; 1 elem/thread; 8 XCD copies) --
    {
        int gidx = bx * 512 + tid;
        if (gidx < 9 * 128 * 64) {
            int off = gidx >> 13;
            int f   = (gidx >> 6) & 127;
            int c   = gidx & 63;
            unsigned short v = f2bf(flt[(f * 64 + c) * 9 + off]);
            int cq = c >> 3, cl = c & 7;
            size_t sidx = (size_t)(off * 128 + f) * 64 + ((cq ^ (f & 7)) * 8 + cl);
#pragma unroll
            for (int xc = 0; xc < 8; ++xc)
                wsS[(size_t)xc * WS_SHORTS + sidx] = v;
        }
    }

    // -- input row transpose (XCD-affine mapping) --
    const int xcd = bx & 7;
    const int k   = bx >> 3;            // [0,448)
    const int b   = xcd * 4 + k / 112;
    const int h   = k - (k / 112) * 112;

    const int lane = tid & 63;
    const int wv   = tid >> 6;          // wave = c-octet index
    const int cr   = lane >> 3;         // c within octet
    const int wq   = lane & 7;          // w-octet within 64-w block
    const float* plane = x + (((size_t)b * 64 + wv * 8 + cr) * 112 + h) * 112;

    for (int it = 0; it < 2; ++it) {
        int wb = it * 64;               // it1 covers w 64..111 (wq<6)
        if (it == 0 || wq < 6) {
            const float* src = plane + wb + wq * 8;
            f32x4 f0 = *(const f32x4*)src;
            f32x4 f1 = *(const f32x4*)(src + 4);
            float r[8] = {f0.x, f0.y, f0.z, f0.w, f1.x, f1.y, f1.z, f1.w};
#pragma unroll
            for (int dd = 1; dd < 8; dd <<= 1) {
#pragma unroll
                for (int jA = 0; jA < 8; ++jA) {
                    if (jA & dd) continue;
                    int jB = jA | dd;
                    float give = (cr & dd) ? r[jA] : r[jB];
                    float got  = __shfl_xor(give, dd * 8, 64);
                    if (cr & dd) r[jA] = got; else r[jB] = got;
                }
            }
            // lane holds c = wv*8 + j (reg j) for w = wb + wq*8 + cr
            int w = wb + wq * 8 + cr;
            unsigned pk[4];
#pragma unroll
            for (int j = 0; j < 4; ++j)
                pk[j] = (unsigned)f2bf(r[2 * j]) | ((unsigned)f2bf(r[2 * j + 1]) << 16);
            *(u32x4*)&T[w * 64 + ((wv ^ (w & 7)) * 8)] = u32x4{pk[0], pk[1], pk[2], pk[3]};
        }
    }
    __syncthreads();

    unsigned short* dst = xt + ((size_t)b * 114 + (h + 1)) * XROW;
    for (int ch = tid; ch < 912; ch += 512) {   // 114 wp * 8 chunks of 16B
        int wp = ch >> 3, cq = ch & 7;
        u32x4 v = {0, 0, 0, 0};
        if (wp >= 1 && wp <= 112) {
            int w = wp - 1;
            v = *(const u32x4*)&T[w * 64 + (cq ^ (w & 7)) * 8];
        }
        *(u32x4*)&dst[(size_t)ch * 8] = v;
    }
    if (h == 0 || h == 111) {
        unsigned short* zr = xt + ((size_t)b * 114 + (h == 0 ? 0 : 113)) * XROW;
        for (int ch = tid; ch < 912; ch += 512)
            *(u32x4*)&zr[(size_t)ch * 8] = u32x4{0, 0, 0, 0};
    }
}

// ---- all-LDS K-loop: 64 filters x NTW w-tiles x 1 output row per wave ----
template <int TW0, int NTW>
__device__ __forceinline__ void kloop_lds(const unsigned short* Ws,
                                          const unsigned short* Bs,
                                          float* obase, int rr, int l16, int q) {
    f32x4 acc[4][NTW];
#pragma unroll
    for (int mt = 0; mt < 4; ++mt)
#pragma unroll
        for (int t = 0; t < NTW; ++t) acc[mt][t] = {0.f, 0.f, 0.f, 0.f};

    const int e = l16 & 7;
#pragma unroll
    for (int off = 0; off < 9; ++off) {
        const int kh = off / 3;            // compile-time (unrolled)
        const int kw = off - kh * 3;
        const int rp = rr + kh;
#pragma unroll
        for (int cs = 0; cs < 2; ++cs) {
            const int cq = cs * 4 + q;
            const int ca = cq ^ e;         // conflict-free A chunk
            bf16x8 a0 = *(const bf16x8*)&Ws[(off * 64 +      l16) * 64 + ca * 8];
            bf16x8 a1 = *(const bf16x8*)&Ws[(off * 64 + 16 + l16) * 64 + ca * 8];
            bf16x8 a2 = *(const bf16x8*)&Ws[(off * 64 + 32 + l16) * 64 + ca * 8];
            bf16x8 a3 = *(const bf16x8*)&Ws[(off * 64 + 48 + l16) * 64 + ca * 8];
#pragma unroll
            for (int t = 0; t < NTW; ++t) {
                int wp = (TW0 + t) * 16 + l16 + kw;
                int cb = cq ^ (wp & 7);
                bf16x8 bv = *(const bf16x8*)&Bs[(rp * WPROW + wp) * 64 + cb * 8];
                acc[0][t] = __builtin_amdgcn_mfma_f32_16x16x32_bf16(a0, bv, acc[0][t], 0, 0, 0);
                acc[1][t] = __builtin_amdgcn_mfma_f32_16x16x32_bf16(a1, bv, acc[1][t], 0, 0, 0);
                acc[2][t] = __builtin_amdgcn_mfma_f32_16x16x32_bf16(a2, bv, acc[2][t], 0, 0, 0);
                acc[3][t] = __builtin_amdgcn_mfma_f32_16x16x32_bf16(a3, bv, acc[3][t], 0, 0, 0);
            }
        }
    }
#pragma unroll
    for (int mt = 0; mt < 4; ++mt)
#pragma unroll
        for (int t = 0; t < NTW; ++t) {
            float* o = obase + (size_t)(mt * 16) * 12544 + (TW0 + t) * 16 + l16;
#pragma unroll
            for (int r2 = 0; r2 < 4; ++r2)
                o[(size_t)r2 * 12544] = acc[mt][t][r2];
        }
}

__global__ __launch_bounds__(512, 2)
void conv_lds(const unsigned short* __restrict__ xt,
              const unsigned short* __restrict__ wsS,
              float* __restrict__ out) {
    __shared__ __align__(16) unsigned short Ws[9 * 64 * 64];      // 73728 B
    __shared__ __align__(16) unsigned short Bs[6 * WPROW * 64];   // 87552 B

    const int tid = threadIdx.x;
    const int id  = blockIdx.x;            // 1792 = 8 xcd x 4 b x 2 fg x 28 quad
    const int xcd = id & 7;
    const int s   = id >> 3;               // [0,224)
    const int b   = xcd * 4 + s / 56;      // XCD reads only the b's it wrote
    const int rem = s - (s / 56) * 56;
    const int fg  = rem / 28;              // 64-filter group
    const int quad = rem - fg * 28;        // [0,28): output rows quad*4..+3

    const int lane = tid & 63;
    const int wid  = tid >> 6;

    const unsigned short* xrow  = xt + ((size_t)b * 114 + quad * 4) * XROW;
    const unsigned short* wbase = wsS + (size_t)xcd * WS_SHORTS + fg * 4096;

    // ---- stage: 84 input segs (Xt likely local-L2) then 72 weight segs
    //      (per-XCD copy, L2-hot) + 6 width-4 tails. One barrier total. ----
    {
        const int l3 = lane >> 3, j = lane & 7;
        for (int i = wid; i < 84; i += 8) {
            int rp = i / 14, seg = i - rp * 14;
            int wp = seg * 8 + l3;                 // <= 111
            gload_lds16(xrow + (size_t)rp * XROW + wp * 64 + ((j ^ (wp & 7)) * 8),
                        &Bs[(rp * WPROW + seg * 8) * 64]);
        }
        for (int i = wid; i < 72; i += 8) {
            int off = i >> 3, k2 = i & 7;
            gload_lds16(wbase + off * 8192 + k2 * 512 + lane * 8,
                        &Ws[off * 4096 + k2 * 512]);
        }
        if (wid < 6) {   // tails wp=112,113 per row (wp=113 is all-zero halo)
            int rp = wid;
            int wp = 112 + (lane >> 5);
            int cq = (lane & 31) >> 2;
            gload_lds4(xrow + (size_t)rp * XROW + wp * 64 + (cq ^ (wp & 7)) * 8 + (lane & 3) * 2,
                       &Bs[(rp * WPROW + 112) * 64]);
        }
    }
    __syncthreads();   // the only barrier (drains vmcnt for global_load_lds)

    const int l16 = lane & 15;
    const int q   = lane >> 4;
    const int rr  = wid & 3;               // output row quad*4 + rr
    const int wsp = wid >> 2;              // w-split (balanced across SIMDs)
    const int h   = quad * 4 + rr;

    float* obase = out + (((size_t)b * 128 + fg * 64 + q * 4) * 112 + h) * 112;

    if (wsp == 0) kloop_lds<0, 4>(Ws, Bs, obase, rr, l16, q);
    else          kloop_lds<4, 3>(Ws, Bs, obase, rr, l16, q);
}

// ======================= fallback (old kernels, unchanged) ===================
__global__ void prep_weights(const float* __restrict__ flt,
                             unsigned short* __restrict__ wsA) {
    int idx = blockIdx.x * 256 + threadIdx.x;
    if (idx >= 9 * 128 * 64) return;
    int off = idx >> 13;
    int f   = (idx >> 6) & 127;
    int c   = idx & 63;
    wsA[idx] = f2bf(flt[(f * 64 + c) * 9 + off]);
}

#define ROWS_PER_KH 124
#define ROW_SHORTS 64

__global__ __launch_bounds__(512, 4)
void conv_mfma(const float* __restrict__ x,
               const unsigned short* __restrict__ wsA,
               float* __restrict__ out) {
    __shared__ __align__(16) unsigned short Bso[4 * ROWS_PER_KH * ROW_SHORTS];

    const int tid = threadIdx.x;
    const int id  = blockIdx.x;
    const int xcd = id & 7;
    const int s   = id >> 3;
    const int b   = s / 7;
    const int hpl = s - b * 7;
    const int hp  = xcd * 7 + hpl;
    const int h0  = hp * 2;

    if (tid < 32) {
        int kh = tid >> 3, cq = tid & 7;
        int R = kh * ROWS_PER_KH;
        int chunk = cq ^ (R & 7);
        *(u32x4*)&Bso[R * ROW_SHORTS + chunk * 8] = u32x4{0, 0, 0, 0};
    }

    const int li   = tid & 7;
    const int unit = tid >> 3;
    for (int it = 0; it < 8; ++it) {
        int u = it * 64 + unit;
        if (u < 480) {
            int wo = u >> 5;
            int rc = u & 31;
            int rp = rc >> 3;
            int cq = rc & 7;
            int hr = h0 + rp - 1;
            int c  = cq * 8 + li;
            f32x4 f0 = {0.f, 0.f, 0.f, 0.f}, f1 = {0.f, 0.f, 0.f, 0.f};
            if ((unsigned)hr < 112u && wo < 14) {
                const float* src = x + (((size_t)b * 64 + c) * 112 + hr) * 112 + wo * 8;
                f0 = *(const f32x4*)src;
                f1 = *(const f32x4*)(src + 4);
            }
            float r[8] = {f0.x, f0.y, f0.z, f0.w, f1.x, f1.y, f1.z, f1.w};
#pragma unroll
            for (int d = 1; d < 8; d <<= 1) {
#pragma unroll
                for (int jA = 0; jA < 8; ++jA) {
                    if (jA & d) continue;
                    int jB = jA | d;
                    float give = (li & d) ? r[jA] : r[jB];
                    float got  = __shfl_xor(give, d, 64);
                    if (li & d) r[jA] = got; else r[jB] = got;
                }
            }
            int R = rp * ROWS_PER_KH + wo * 8 + li + 1;
            int chunk = cq ^ (R & 7);
            unsigned pk[4];
#pragma unroll
            for (int j = 0; j < 4; ++j)
                pk[j] = (unsigned)f2bf(r[2 * j]) | ((unsigned)f2bf(r[2 * j + 1]) << 16);
            *(u32x4*)&Bso[R * ROW_SHORTS + chunk * 8] = u32x4{pk[0], pk[1], pk[2], pk[3]};
        }
    }
    __syncthreads();

    const int lane = tid & 63;
    const int wid  = tid >> 6;
    const int fg   = wid & 3;
    const int rr   = wid >> 2;
    const int q    = lane >> 4;
    const int l16  = lane & 15;
    const int h    = h0 + rr;

    f32x4 acc[2][7];
#pragma unroll
    for (int mt = 0; mt < 2; ++mt)
#pragma unroll
        for (int tw = 0; tw < 7; ++tw)
            acc[mt][tw] = {0.f, 0.f, 0.f, 0.f};

    const unsigned short* wA = wsA + (fg * 32 + l16) * 64 + q * 8;

#pragma unroll
    for (int off = 0; off < 9; ++off) {
        const int kh = off / 3;
        const int kw = off - kh * 3;
        const int Rbase = (rr + kh) * ROWS_PER_KH + kw;
#pragma unroll
        for (int cs = 0; cs < 2; ++cs) {
            bf16x8 a0 = *(const bf16x8*)(wA + off * 8192 + cs * 32);
            bf16x8 a1 = *(const bf16x8*)(wA + off * 8192 + 1024 + cs * 32);
            const int cq = cs * 4 + q;
#pragma unroll
            for (int tw = 0; tw < 7; ++tw) {
                int R = Rbase + tw * 16 + l16;
                int chunk = cq ^ (R & 7);
                bf16x8 bv = *(const bf16x8*)&Bso[R * ROW_SHORTS + chunk * 8];
                acc[0][tw] = __builtin_amdgcn_mfma_f32_16x16x32_bf16(a0, bv, acc[0][tw], 0, 0, 0);
                acc[1][tw] = __builtin_amdgcn_mfma_f32_16x16x32_bf16(a1, bv, acc[1][tw], 0, 0, 0);
            }
        }
    }

#pragma unroll
    for (int mt = 0; mt < 2; ++mt) {
#pragma unroll
        for (int tw = 0; tw < 7; ++tw) {
            int f = fg * 32 + mt * 16 + q * 4;
            int w = tw * 16 + l16;
            float* o = out + (((size_t)b * 128 + f) * 112 + h) * 112 + w;
#pragma unroll
            for (int r2 = 0; r2 < 4; ++r2)
                o[(size_t)r2 * 12544] = acc[mt][tw][r2];
        }
    }
}

extern "C" void kernel_launch(void* const* d_in, const int* in_sizes, int n_in,
                              void* d_out, int out_size, void* d_ws, size_t ws_size,
                              hipStream_t stream) {
    const float* x   = (const float*)d_in[0];   // dataset [32,64,112,112]
    const float* flt = (const float*)d_in[1];   // filters [128,64,3,3]
    float* out = (float*)d_out;
    unsigned short* ws  = (unsigned short*)d_ws;
    unsigned short* wsA = ws;                        // fallback weights (147456 B)
    unsigned short* wsS = ws + WS_SHORTS;            // 8 swizzled copies (1.18 MB)
    unsigned short* xxt = ws + WS_SHORTS * 9;        // Xt [32][114][114][64]

    const size_t XT_SHORTS = (size_t)32 * 114 * 114 * 64;          // 26,615,808
    const size_t need = ((size_t)WS_SHORTS * 9 + XT_SHORTS) * 2;   // ~54.6 MB
    if (ws_size >= need) {
        hipLaunchKernelGGL(prep_all, dim3(3584), dim3(512), 0, stream, x, flt, xxt, wsS);
        hipLaunchKernelGGL(conv_lds, dim3(1792), dim3(512), 0, stream, xxt, wsS, out);
    } else {
        hipLaunchKernelGGL(prep_weights, dim3(288), dim3(256), 0, stream, flt, wsA);
        hipLaunchKernelGGL(conv_mfma, dim3(1792), dim3(512), 0, stream, x, wsA, out);
    }
}